// Round 10
// baseline (258.758 us; speedup 1.0000x reference)
//
#include <hip/hip_runtime.h>
#include <hip/hip_bf16.h>
#include <stdint.h>

typedef __bf16 bf16;
typedef __bf16 bf16x8 __attribute__((ext_vector_type(8)));
typedef __bf16 bf16x4 __attribute__((ext_vector_type(4)));
typedef float f32x4 __attribute__((ext_vector_type(4)));
typedef float f32x8 __attribute__((ext_vector_type(8)));

#define BB 32
#define TT 2048
#define DD 1024
#define HH 128
#define SCALE 0.08838834764831845f   // H^-0.5
#define LOG2E 1.4426950408889634f
#define KS (SCALE * LOG2E)

__device__ __forceinline__ void gl_lds16(const bf16* g, bf16* l) {
  __builtin_amdgcn_global_load_lds((__attribute__((address_space(1))) const void*)g,
                                   (__attribute__((address_space(3))) void*)l,
                                   16, 0, 0);
}

// counted-vmcnt barrier: never drain the early-issued x loads (N=8) in h0
#define KBAR(N) do { \
  asm volatile("s_waitcnt vmcnt(" #N ") lgkmcnt(0)" ::: "memory"); \
  __builtin_amdgcn_s_barrier(); \
  __builtin_amdgcn_sched_barrier(0); \
} while (0)

// ---------------- kernel 0: Wt[mat][h][d] = W[d][h] (fp32 -> bf16) -------------
__global__ __launch_bounds__(256) void prep_w(const float* __restrict__ Wk,
                                              const float* __restrict__ Wq,
                                              const float* __restrict__ Wv,
                                              const float* __restrict__ bk,
                                              const float* __restrict__ bq,
                                              const float* __restrict__ bv,
                                              bf16* __restrict__ Wt,
                                              float* __restrict__ bcat) {
  int tid = blockIdx.x * 256 + threadIdx.x;   // 0..49151
  if (tid < 384) {
    int mat = tid >> 7, h = tid & 127;
    float bb = (mat == 0) ? bk[h] : (mat == 1) ? bq[h] : bv[h];
    bcat[tid] = (mat == 0) ? bb * KS : bb;
  }
  int mat = tid >> 14;
  int r = tid & 16383;
  int h = r & 127;
  int d0 = (r >> 7) << 3;
  const float* W = (mat == 0) ? Wk : (mat == 1) ? Wq : Wv;
  const float ks = (mat == 0) ? KS : 1.0f;
  bf16x8 v;
#pragma unroll
  for (int i = 0; i < 8; ++i) v[i] = (bf16)(W[(size_t)(d0 + i) * HH + h] * ks);
  *(bf16x8*)(Wt + ((size_t)mat * HH + h) * DD + d0) = v;
}

// ---------------- kernel 1: fused QKV projection GEMM (bf16 MFMA) --------------
// R10: x is DRAM-PAGE-BOUND (R9 diagnosis: 128B-per-4KB-page slices -> 1.6TB/s).
// Fix: BM=64, grid 1024; each block reads its x rows in 2KB-CONTIGUOUS half-rows
// (reg-staged, fp32->bf16, LDS [64][512] XOR-swizzled tile), half-K x 2 passes.
// W (L2-resident) streamed per BK=32 slice via gl_lds+XOR (0-conflict, R7-proven).
// Next half's x loads issued EARLY and kept in flight across h0's k-loop via
// counted vmcnt(8) barriers (T4). 8 waves (2x4), wave tile 32x96, LDS 112 KB.
__global__ __launch_bounds__(512, 2) void qkv_proj(
    const float* __restrict__ x, const bf16* __restrict__ Wt,
    const float* __restrict__ bcat,
    bf16* __restrict__ kb, bf16* __restrict__ qb, bf16* __restrict__ Vt) {
  const int bid = blockIdx.x;
  const int tid = threadIdx.x;
  const int lane = tid & 63;
  const int w = tid >> 6;                    // 0..7
  const int wr = w >> 2, wc = w & 3;
  const int l15 = lane & 15, l4 = lane >> 4;
  const size_t row0 = (size_t)bid * 64;
  const int colbase = wc * 96;
  const int rowbase = wr * 32;

  __shared__ __attribute__((aligned(16))) bf16 As[64 * 512];   // 64 KB
  __shared__ __attribute__((aligned(16))) bf16 Ws[2][384 * 32]; // 48 KB

  const int sxr = tid >> 3;   // row 0..63
  const int sxs = tid & 7;    // 64-float segment within the 512-float half-row

  f32x4 acc[2][6];
#pragma unroll
  for (int m = 0; m < 2; ++m)
#pragma unroll
    for (int n = 0; n < 6; ++n) acc[m][n] = f32x4{0.f, 0.f, 0.f, 0.f};

  auto stage_w = [&](int s, int buf) {   // global k-slice s (0..31) -> Ws[buf]
    bf16* dst0 = &Ws[buf][0];
#pragma unroll
    for (int i = 0; i < 3; ++i) {
      int base = i * 512 + (w << 6);            // wave-uniform
      int C = base + lane;
      int col = C >> 2, j = C & 3;
      const bf16* src = Wt + (size_t)col * DD + s * 32 + ((j ^ ((col >> 1) & 3)) << 3);
      gl_lds16(src, dst0 + (size_t)base * 8);
    }
  };
  auto load_x = [&](int half, f32x8* xv) {   // 256B contiguous per thread
    const float* xp = x + (row0 + sxr) * DD + half * 512 + sxs * 64;
#pragma unroll
    for (int i = 0; i < 8; ++i) xv[i] = *(const f32x8*)(xp + i * 8);
  };
  auto cvt_write = [&](const f32x8* xv) {    // -> As, chunk swizzle c^(r&7)
#pragma unroll
    for (int i = 0; i < 8; ++i) {
      bf16x8 t;
#pragma unroll
      for (int j = 0; j < 8; ++j) t[j] = (bf16)xv[i][j];
      int c = sxs * 8 + i;
      *(bf16x8*)&As[sxr * 512 + ((c ^ (sxr & 7)) << 3)] = t;
    }
  };
  auto kstep = [&](int half, int s) {
    if (s < 15) stage_w(half * 16 + s + 1, (s + 1) & 1);
    bf16x8 afm[2], bfr[6];
#pragma unroll
    for (int m = 0; m < 2; ++m) {
      int r = rowbase + m * 16 + l15;
      int c = s * 4 + l4;
      afm[m] = *(const bf16x8*)&As[r * 512 + ((c ^ (r & 7)) << 3)];
    }
#pragma unroll
    for (int n = 0; n < 6; ++n) {
      int col = colbase + n * 16 + l15;
      bfr[n] = *(const bf16x8*)&Ws[s & 1][col * 32 + ((l4 ^ ((col >> 1) & 3)) << 3)];
    }
#pragma unroll
    for (int m = 0; m < 2; ++m)
#pragma unroll
      for (int n = 0; n < 6; ++n)
        acc[m][n] = __builtin_amdgcn_mfma_f32_16x16x32_bf16(afm[m], bfr[n],
                                                            acc[m][n], 0, 0, 0);
  };

  f32x8 xv[8];
  // ---- half 0 prologue: x(h0) row-contiguous, W(0); issue x(h1) early ----
  load_x(0, xv);
  stage_w(0, 0);
  cvt_write(xv);          // waits only the x(h0) loads; W(0) stays in flight
  load_x(1, xv);          // h1 loads issued now; hidden under h0 k-loop
  KBAR(8);                // drain W(0); keep x(h1)'s 8 loads outstanding

  for (int s = 0; s < 16; ++s) { kstep(0, s); KBAR(8); }

  // ---- half 1 ----
  stage_w(16, 0);
  cvt_write(xv);          // x(h1) data (loads completed during h0 k-loop)
  KBAR(0);

  for (int s = 0; s < 16; ++s) { kstep(1, s); KBAR(0); }

  // ---- epilogue ----
  float bvv[6];
#pragma unroll
  for (int n = 0; n < 6; ++n) bvv[n] = bcat[colbase + n * 16 + l15];

  const int bidx = bid >> 5;
  const int tloc0 = (bid & 31) * 64;
#pragma unroll
  for (int m = 0; m < 2; ++m)
#pragma unroll
    for (int n = 0; n < 6; ++n) {
      int col = colbase + n * 16 + l15;
      int mat = col >> 7;
      int hcol = col & 127;
      int rloc = rowbase + m * 16 + l4 * 4;
      if (mat == 2) {
        bf16x4 v4;
#pragma unroll
        for (int e = 0; e < 4; ++e) v4[e] = (bf16)(acc[m][n][e] + bvv[n]);
        *(bf16x4*)(Vt + ((size_t)bidx * HH + hcol) * TT + tloc0 + rloc) = v4;
      } else {
        bf16* dst = (mat == 0) ? kb : qb;
#pragma unroll
        for (int e = 0; e < 4; ++e)
          dst[(row0 + rloc + e) * HH + hcol] = (bf16)(acc[m][n][e] + bvv[n]);
      }
    }
}

// ---------------- kernel 2: fused causal flash attention -----------------------
// quirk: scores[t][s] = k[t].q[s] -> k rows are the softmax rows (k pre-scaled
// by SCALE*LOG2E, so softmax is computed with exp2 directly).
// grid 512; block 256 = 4 waves * 16 rows = 64-row t-tile; two complementary
// jobs per block = exactly 33 s-iterations each (perfect balance).
__global__ __launch_bounds__(256, 3) void attn(const bf16* __restrict__ kb,
                                               const bf16* __restrict__ qb,
                                               const bf16* __restrict__ Vt,
                                               float* __restrict__ out) {
  const int bid = blockIdx.x;
  const int b = bid & 31;
  const int p = bid >> 5;                 // 0..15
  const int tid = threadIdx.x;
  const int lane = tid & 63;
  const int w = tid >> 6;
  const int l15 = lane & 15, l4 = lane >> 4;

  __shared__ __attribute__((aligned(16))) bf16 Es[64 * 128];   // q tile [s][h], swizzled
  __shared__ __attribute__((aligned(16))) bf16 Vs[128 * 64];   // Vt tile [h][s], swizzled
  __shared__ __attribute__((aligned(16))) bf16 Ps[4][16 * 72]; // wave-private P

  for (int job = 0; job < 2; ++job) {
    const int tile = job ? p : (31 - p);
    const int t0 = tile * 64;

    bf16x8 af[4];
    {
      const bf16* kp = kb + ((size_t)b * TT + t0 + w * 16 + l15) * HH + l4 * 8;
#pragma unroll
      for (int kc = 0; kc < 4; ++kc) af[kc] = *(const bf16x8*)(kp + kc * 32);
    }

    f32x4 o[8];
#pragma unroll
    for (int j = 0; j < 8; ++j) o[j] = f32x4{0.f, 0.f, 0.f, 0.f};
    float mrow[4], lrow[4];
#pragma unroll
    for (int e = 0; e < 4; ++e) { mrow[e] = -1e30f; lrow[e] = 0.f; }

    const int nst = tile + 1;
    for (int jt = 0; jt < nst; ++jt) {
      const int s0 = jt * 64;
      {
        const bf16* Eg = qb + ((size_t)b * TT + s0) * HH;      // [64][128]
#pragma unroll
        for (int it = 0; it < 4; ++it) {
          int L = w * 256 + it * 64 + lane;
          int er = L >> 4, ec = L & 15;
          int ecs = ec ^ (er & 7);
          gl_lds16(Eg + er * HH + ecs * 8, Es + (size_t)(w * 256 + it * 64) * 8);
        }
        const bf16* Vg = Vt + (size_t)b * HH * TT + s0;        // rows h, 64 cols
#pragma unroll
        for (int it = 0; it < 4; ++it) {
          int L = w * 256 + it * 64 + lane;
          int vr = L >> 3, vc = L & 7;
          int vcs = vc ^ (vr & 7);
          gl_lds16(Vg + (size_t)vr * TT + vcs * 8, Vs + (size_t)(w * 256 + it * 64) * 8);
        }
      }
      __syncthreads();

      f32x4 s[4];
#pragma unroll
      for (int j = 0; j < 4; ++j) s[j] = f32x4{0.f, 0.f, 0.f, 0.f};
#pragma unroll
      for (int kc = 0; kc < 4; ++kc) {
        bf16x8 ef[4];
#pragma unroll
        for (int fn = 0; fn < 4; ++fn) {
          int er = fn * 16 + l15;
          int c = kc * 4 + l4;
          int cs = c ^ (er & 7);
          ef[fn] = *(const bf16x8*)&Es[er * 128 + cs * 8];
        }
#pragma unroll
        for (int fn = 0; fn < 4; ++fn)
          s[fn] = __builtin_amdgcn_mfma_f32_16x16x32_bf16(af[kc], ef[fn],
                                                          s[fn], 0, 0, 0);
      }

      if (s0 + 63 > t0 + w * 16) {
#pragma unroll
        for (int fn = 0; fn < 4; ++fn)
#pragma unroll
          for (int e = 0; e < 4; ++e) {
            int tg = t0 + w * 16 + l4 * 4 + e;
            int sg = s0 + fn * 16 + l15;
            if (sg > tg) s[fn][e] = -1e30f;
          }
      }

      float mx[4];
#pragma unroll
      for (int e = 0; e < 4; ++e) {
        float m = fmaxf(fmaxf(s[0][e], s[1][e]), fmaxf(s[2][e], s[3][e]));
#pragma unroll
        for (int d = 1; d < 16; d <<= 1) m = fmaxf(m, __shfl_xor(m, d));
        mx[e] = m;
      }
      float g = fmaxf(fmaxf(mx[0] - mrow[0], mx[1] - mrow[1]),
                      fmaxf(mx[2] - mrow[2], mx[3] - mrow[3]));
      if (!__all(g <= 8.0f)) {
#pragma unroll
        for (int e = 0; e < 4; ++e) {
          float mn = fmaxf(mrow[e], mx[e]);
          float rsc = exp2f(mrow[e] - mn);
          lrow[e] *= rsc;
#pragma unroll
          for (int fh = 0; fh < 8; ++fh) o[fh][e] *= rsc;
          mrow[e] = mn;
        }
      }
#pragma unroll
      for (int e = 0; e < 4; ++e) {
        float ps = 0.f;
#pragma unroll
        for (int fn = 0; fn < 4; ++fn) {
          float pv = exp2f(s[fn][e] - mrow[e]);
          s[fn][e] = pv;
          ps += pv;
        }
#pragma unroll
        for (int d = 1; d < 16; d <<= 1) ps += __shfl_xor(ps, d);
        lrow[e] += ps;
      }

#pragma unroll
      for (int fn = 0; fn < 4; ++fn)
#pragma unroll
        for (int e = 0; e < 4; ++e)
          Ps[w][(l4 * 4 + e) * 72 + fn * 16 + l15] = (bf16)s[fn][e];

#pragma unroll
      for (int kc = 0; kc < 2; ++kc) {
        bf16x8 pf = *(const bf16x8*)&Ps[w][l15 * 72 + kc * 32 + l4 * 8];
#pragma unroll
        for (int fh = 0; fh < 8; ++fh) {
          int vr = fh * 16 + l15;
          int c = kc * 4 + l4;
          int cs = c ^ (vr & 7);
          bf16x8 vf = *(const bf16x8*)&Vs[vr * 64 + cs * 8];
          o[fh] = __builtin_amdgcn_mfma_f32_16x16x32_bf16(pf, vf, o[fh], 0, 0, 0);
        }
      }
      __syncthreads();
    }

#pragma unroll
    for (int e = 0; e < 4; ++e) {
      float rl = 1.0f / lrow[e];
      int tg = t0 + w * 16 + l4 * 4 + e;
#pragma unroll
      for (int fh = 0; fh < 8; ++fh)
        out[((size_t)b * TT + tg) * HH + fh * 16 + l15] = o[fh][e] * rl;
    }
  }
}

extern "C" void kernel_launch(void* const* d_in, const int* in_sizes, int n_in,
                              void* d_out, int out_size, void* d_ws, size_t ws_size,
                              hipStream_t stream) {
  (void)in_sizes; (void)n_in; (void)out_size; (void)ws_size;
  const float* x  = (const float*)d_in[0];
  const float* Wk = (const float*)d_in[1];
  const float* bk = (const float*)d_in[2];
  const float* Wq = (const float*)d_in[3];
  const float* bq = (const float*)d_in[4];
  const float* Wv = (const float*)d_in[5];
  const float* bv = (const float*)d_in[6];
  float* out = (float*)d_out;

  const size_t NTH = (size_t)BB * TT * HH;   // 8388608
  bf16* kb = (bf16*)d_ws;
  bf16* qb = kb + NTH;
  bf16* Vt = qb + NTH;
  bf16* Wt = Vt + NTH;                        // 3*128*1024 bf16
  float* bcat = (float*)(Wt + (size_t)3 * HH * DD);

  prep_w<<<192, 256, 0, stream>>>(Wk, Wq, Wv, bk, bq, bv, Wt, bcat);
  qkv_proj<<<1024, 512, 0, stream>>>(x, Wt, bcat, kb, qb, Vt);
  attn<<<512, 256, 0, stream>>>(kb, qb, Vt, out);
}

// Round 11
// 212.810 us; speedup vs baseline: 1.2159x; 1.2159x over previous
//
#include <hip/hip_runtime.h>
#include <hip/hip_bf16.h>
#include <stdint.h>

typedef __bf16 bf16;
typedef __bf16 bf16x8 __attribute__((ext_vector_type(8)));
typedef __bf16 bf16x4 __attribute__((ext_vector_type(4)));
typedef float f32x4 __attribute__((ext_vector_type(4)));
typedef float f32x8 __attribute__((ext_vector_type(8)));

#define BB 32
#define TT 2048
#define DD 1024
#define HH 128
#define SCALE 0.08838834764831845f   // H^-0.5
#define LOG2E 1.4426950408889634f
#define KS (SCALE * LOG2E)

__device__ __forceinline__ void gl_lds16(const bf16* g, bf16* l) {
  __builtin_amdgcn_global_load_lds((__attribute__((address_space(1))) const void*)g,
                                   (__attribute__((address_space(3))) void*)l,
                                   16, 0, 0);
}
__device__ __forceinline__ void gl_lds16f(const float* g, float* l) {
  __builtin_amdgcn_global_load_lds((__attribute__((address_space(1))) const void*)g,
                                   (__attribute__((address_space(3))) void*)l,
                                   16, 0, 0);
}

// ---------------- kernel 0: Wt[mat][h][d] = W[d][h] (fp32 -> bf16) -------------
__global__ __launch_bounds__(256) void prep_w(const float* __restrict__ Wk,
                                              const float* __restrict__ Wq,
                                              const float* __restrict__ Wv,
                                              const float* __restrict__ bk,
                                              const float* __restrict__ bq,
                                              const float* __restrict__ bv,
                                              bf16* __restrict__ Wt,
                                              float* __restrict__ bcat) {
  int tid = blockIdx.x * 256 + threadIdx.x;   // 0..49151
  if (tid < 384) {
    int mat = tid >> 7, h = tid & 127;
    float bb = (mat == 0) ? bk[h] : (mat == 1) ? bq[h] : bv[h];
    bcat[tid] = (mat == 0) ? bb * KS : bb;
  }
  int mat = tid >> 14;
  int r = tid & 16383;
  int h = r & 127;
  int d0 = (r >> 7) << 3;
  const float* W = (mat == 0) ? Wk : (mat == 1) ? Wq : Wv;
  const float ks = (mat == 0) ? KS : 1.0f;
  bf16x8 v;
#pragma unroll
  for (int i = 0; i < 8; ++i) v[i] = (bf16)(W[(size_t)(d0 + i) * HH + h] * ks);
  *(bf16x8*)(Wt + ((size_t)mat * HH + h) * DD + d0) = v;
}

// ---------------- kernel 1: fused QKV projection GEMM (bf16 MFMA) --------------
// R11: regime map from R2..R10: >=2 blocks/CU => bytes-bound at ~7 TB/s
// aggregate staging; 1 block/CU => latency-bound (worse). Optimum: R5's exact
// proven structure (both operands gl_lds, dbuf, one barrier/step) at the
// largest BM that keeps LDS <= 80 KB (2 blocks/CU): BM=128.
//   As fp32 [2][128x32] = 32 KB, Ws bf16 [2][384x32] = 48 KB -> 80 KB exactly.
//   W re-traffic 402 MB (half of R5), x 268 MB once.
// 512 threads, 8 waves (2x4), wave tile 64x96, acc[4][6] (~160 VGPR @ (512,2)).
__global__ __launch_bounds__(512, 2) void qkv_proj(
    const float* __restrict__ x, const bf16* __restrict__ Wt,
    const float* __restrict__ bcat,
    bf16* __restrict__ kb, bf16* __restrict__ qb, bf16* __restrict__ Vt) {
  const int bid = blockIdx.x;
  const int tid = threadIdx.x;
  const int lane = tid & 63;
  const int w = tid >> 6;                    // 0..7
  const int wr = w >> 2, wc = w & 3;
  const int l15 = lane & 15, l4 = lane >> 4;
  const size_t row0 = (size_t)bid * 128;
  const int colbase = wc * 96;
  const int rowbase = wr * 64;

  __shared__ __attribute__((aligned(16))) float As[2][128 * 32];  // 32 KB
  __shared__ __attribute__((aligned(16))) bf16  Ws[2][384 * 32];  // 48 KB

  f32x4 acc[4][6];
#pragma unroll
  for (int m = 0; m < 4; ++m)
#pragma unroll
    for (int n = 0; n < 6; ++n) acc[m][n] = f32x4{0.f, 0.f, 0.f, 0.f};

  // stage k-slice [k0,k0+32): x 1024 chunks (2/thread), W 1536 chunks (3/thread)
  auto stage = [&](int buf, int k0) {
#pragma unroll
    for (int i = 0; i < 2; ++i) {
      int base = i * 512 + (w << 6);            // wave-uniform chunk base
      int C = base + lane;
      int r = C >> 3, c = C & 7;                // LDS slot (r, c) of 8 per row
      const float* src = x + (row0 + r) * DD + k0 + ((c ^ (r & 7)) << 2);
      gl_lds16f(src, &As[buf][0] + (size_t)base * 4);
    }
#pragma unroll
    for (int i = 0; i < 3; ++i) {
      int base = i * 512 + (w << 6);
      int C = base + lane;
      int col = C >> 2, j = C & 3;              // LDS slot (col, j) of 4 per row
      const bf16* src = Wt + (size_t)col * DD + k0 + ((j ^ ((col >> 1) & 3)) << 3);
      gl_lds16(src, &Ws[buf][0] + (size_t)base * 8);
    }
  };

  stage(0, 0);
  __syncthreads();

  for (int step = 0; step < 32; ++step) {
    const int cur = step & 1;
    if (step + 1 < 32) stage(cur ^ 1, (step + 1) * 32);

    // af: fp32 from LDS -> bf16 fragments (swizzled 16B chunks)
    bf16x8 afm[4];
#pragma unroll
    for (int m = 0; m < 4; ++m) {
      int r = rowbase + m * 16 + l15;
      int c0 = (2 * l4) ^ (r & 7), c1 = (2 * l4 + 1) ^ (r & 7);
      f32x4 lo = *(const f32x4*)&As[cur][r * 32 + c0 * 4];
      f32x4 hi = *(const f32x4*)&As[cur][r * 32 + c1 * 4];
#pragma unroll
      for (int i = 0; i < 4; ++i) { afm[m][i] = (bf16)lo[i]; afm[m][4 + i] = (bf16)hi[i]; }
    }
    bf16x8 bfr[6];
#pragma unroll
    for (int n = 0; n < 6; ++n) {
      int col = colbase + n * 16 + l15;
      bfr[n] = *(const bf16x8*)&Ws[cur][col * 32 + ((l4 ^ ((col >> 1) & 3)) << 3)];
    }
#pragma unroll
    for (int m = 0; m < 4; ++m)
#pragma unroll
      for (int n = 0; n < 6; ++n)
        acc[m][n] = __builtin_amdgcn_mfma_f32_16x16x32_bf16(afm[m], bfr[n],
                                                            acc[m][n], 0, 0, 0);
    __syncthreads();
  }

  // epilogue
  float bvv[6];
#pragma unroll
  for (int n = 0; n < 6; ++n) bvv[n] = bcat[colbase + n * 16 + l15];

  const int bidx = bid >> 4;
  const int tloc0 = (bid & 15) * 128;
#pragma unroll
  for (int m = 0; m < 4; ++m)
#pragma unroll
    for (int n = 0; n < 6; ++n) {
      int col = colbase + n * 16 + l15;
      int mat = col >> 7;
      int hcol = col & 127;
      int rloc = rowbase + m * 16 + l4 * 4;
      if (mat == 2) {
        bf16x4 v4;
#pragma unroll
        for (int e = 0; e < 4; ++e) v4[e] = (bf16)(acc[m][n][e] + bvv[n]);
        *(bf16x4*)(Vt + ((size_t)bidx * HH + hcol) * TT + tloc0 + rloc) = v4;
      } else {
        bf16* dst = (mat == 0) ? kb : qb;
#pragma unroll
        for (int e = 0; e < 4; ++e)
          dst[(row0 + rloc + e) * HH + hcol] = (bf16)(acc[m][n][e] + bvv[n]);
      }
    }
}

// ---------------- kernel 2: fused causal flash attention -----------------------
// quirk: scores[t][s] = k[t].q[s] -> k rows are the softmax rows (k pre-scaled
// by SCALE*LOG2E, so softmax is computed with exp2 directly).
// grid 512; block 256 = 4 waves * 16 rows = 64-row t-tile; two complementary
// jobs per block = exactly 33 s-iterations each (perfect balance).
__global__ __launch_bounds__(256, 3) void attn(const bf16* __restrict__ kb,
                                               const bf16* __restrict__ qb,
                                               const bf16* __restrict__ Vt,
                                               float* __restrict__ out) {
  const int bid = blockIdx.x;
  const int b = bid & 31;
  const int p = bid >> 5;                 // 0..15
  const int tid = threadIdx.x;
  const int lane = tid & 63;
  const int w = tid >> 6;
  const int l15 = lane & 15, l4 = lane >> 4;

  __shared__ __attribute__((aligned(16))) bf16 Es[64 * 128];   // q tile [s][h], swizzled
  __shared__ __attribute__((aligned(16))) bf16 Vs[128 * 64];   // Vt tile [h][s], swizzled
  __shared__ __attribute__((aligned(16))) bf16 Ps[4][16 * 72]; // wave-private P

  for (int job = 0; job < 2; ++job) {
    const int tile = job ? p : (31 - p);
    const int t0 = tile * 64;

    bf16x8 af[4];
    {
      const bf16* kp = kb + ((size_t)b * TT + t0 + w * 16 + l15) * HH + l4 * 8;
#pragma unroll
      for (int kc = 0; kc < 4; ++kc) af[kc] = *(const bf16x8*)(kp + kc * 32);
    }

    f32x4 o[8];
#pragma unroll
    for (int j = 0; j < 8; ++j) o[j] = f32x4{0.f, 0.f, 0.f, 0.f};
    float mrow[4], lrow[4];
#pragma unroll
    for (int e = 0; e < 4; ++e) { mrow[e] = -1e30f; lrow[e] = 0.f; }

    const int nst = tile + 1;
    for (int jt = 0; jt < nst; ++jt) {
      const int s0 = jt * 64;
      {
        const bf16* Eg = qb + ((size_t)b * TT + s0) * HH;      // [64][128]
#pragma unroll
        for (int it = 0; it < 4; ++it) {
          int L = w * 256 + it * 64 + lane;
          int er = L >> 4, ec = L & 15;
          int ecs = ec ^ (er & 7);
          gl_lds16(Eg + er * HH + ecs * 8, Es + (size_t)(w * 256 + it * 64) * 8);
        }
        const bf16* Vg = Vt + (size_t)b * HH * TT + s0;        // rows h, 64 cols
#pragma unroll
        for (int it = 0; it < 4; ++it) {
          int L = w * 256 + it * 64 + lane;
          int vr = L >> 3, vc = L & 7;
          int vcs = vc ^ (vr & 7);
          gl_lds16(Vg + (size_t)vr * TT + vcs * 8, Vs + (size_t)(w * 256 + it * 64) * 8);
        }
      }
      __syncthreads();

      f32x4 s[4];
#pragma unroll
      for (int j = 0; j < 4; ++j) s[j] = f32x4{0.f, 0.f, 0.f, 0.f};
#pragma unroll
      for (int kc = 0; kc < 4; ++kc) {
        bf16x8 ef[4];
#pragma unroll
        for (int fn = 0; fn < 4; ++fn) {
          int er = fn * 16 + l15;
          int c = kc * 4 + l4;
          int cs = c ^ (er & 7);
          ef[fn] = *(const bf16x8*)&Es[er * 128 + cs * 8];
        }
#pragma unroll
        for (int fn = 0; fn < 4; ++fn)
          s[fn] = __builtin_amdgcn_mfma_f32_16x16x32_bf16(af[kc], ef[fn],
                                                          s[fn], 0, 0, 0);
      }

      if (s0 + 63 > t0 + w * 16) {
#pragma unroll
        for (int fn = 0; fn < 4; ++fn)
#pragma unroll
          for (int e = 0; e < 4; ++e) {
            int tg = t0 + w * 16 + l4 * 4 + e;
            int sg = s0 + fn * 16 + l15;
            if (sg > tg) s[fn][e] = -1e30f;
          }
      }

      float mx[4];
#pragma unroll
      for (int e = 0; e < 4; ++e) {
        float m = fmaxf(fmaxf(s[0][e], s[1][e]), fmaxf(s[2][e], s[3][e]));
#pragma unroll
        for (int d = 1; d < 16; d <<= 1) m = fmaxf(m, __shfl_xor(m, d));
        mx[e] = m;
      }
      float g = fmaxf(fmaxf(mx[0] - mrow[0], mx[1] - mrow[1]),
                      fmaxf(mx[2] - mrow[2], mx[3] - mrow[3]));
      if (!__all(g <= 8.0f)) {
#pragma unroll
        for (int e = 0; e < 4; ++e) {
          float mn = fmaxf(mrow[e], mx[e]);
          float rsc = exp2f(mrow[e] - mn);
          lrow[e] *= rsc;
#pragma unroll
          for (int fh = 0; fh < 8; ++fh) o[fh][e] *= rsc;
          mrow[e] = mn;
        }
      }
#pragma unroll
      for (int e = 0; e < 4; ++e) {
        float ps = 0.f;
#pragma unroll
        for (int fn = 0; fn < 4; ++fn) {
          float pv = exp2f(s[fn][e] - mrow[e]);
          s[fn][e] = pv;
          ps += pv;
        }
#pragma unroll
        for (int d = 1; d < 16; d <<= 1) ps += __shfl_xor(ps, d);
        lrow[e] += ps;
      }

#pragma unroll
      for (int fn = 0; fn < 4; ++fn)
#pragma unroll
        for (int e = 0; e < 4; ++e)
          Ps[w][(l4 * 4 + e) * 72 + fn * 16 + l15] = (bf16)s[fn][e];

#pragma unroll
      for (int kc = 0; kc < 2; ++kc) {
        bf16x8 pf = *(const bf16x8*)&Ps[w][l15 * 72 + kc * 32 + l4 * 8];
#pragma unroll
        for (int fh = 0; fh < 8; ++fh) {
          int vr = fh * 16 + l15;
          int c = kc * 4 + l4;
          int cs = c ^ (vr & 7);
          bf16x8 vf = *(const bf16x8*)&Vs[vr * 64 + cs * 8];
          o[fh] = __builtin_amdgcn_mfma_f32_16x16x32_bf16(pf, vf, o[fh], 0, 0, 0);
        }
      }
      __syncthreads();
    }

#pragma unroll
    for (int e = 0; e < 4; ++e) {
      float rl = 1.0f / lrow[e];
      int tg = t0 + w * 16 + l4 * 4 + e;
#pragma unroll
      for (int fh = 0; fh < 8; ++fh)
        out[((size_t)b * TT + tg) * HH + fh * 16 + l15] = o[fh][e] * rl;
    }
  }
}

extern "C" void kernel_launch(void* const* d_in, const int* in_sizes, int n_in,
                              void* d_out, int out_size, void* d_ws, size_t ws_size,
                              hipStream_t stream) {
  (void)in_sizes; (void)n_in; (void)out_size; (void)ws_size;
  const float* x  = (const float*)d_in[0];
  const float* Wk = (const float*)d_in[1];
  const float* bk = (const float*)d_in[2];
  const float* Wq = (const float*)d_in[3];
  const float* bq = (const float*)d_in[4];
  const float* Wv = (const float*)d_in[5];
  const float* bv = (const float*)d_in[6];
  float* out = (float*)d_out;

  const size_t NTH = (size_t)BB * TT * HH;   // 8388608
  bf16* kb = (bf16*)d_ws;
  bf16* qb = kb + NTH;
  bf16* Vt = qb + NTH;
  bf16* Wt = Vt + NTH;                        // 3*128*1024 bf16
  float* bcat = (float*)(Wt + (size_t)3 * HH * DD);

  prep_w<<<192, 256, 0, stream>>>(Wk, Wq, Wv, bk, bq, bv, Wt, bcat);
  qkv_proj<<<512, 512, 0, stream>>>(x, Wt, bcat, kb, qb, Vt);
  attn<<<512, 256, 0, stream>>>(kb, qb, Vt, out);
}